// Round 1
// baseline (201.832 us; speedup 1.0000x reference)
//
#include <hip/hip_runtime.h>

// SSIM loss, fused single-pass: separable 11x11 Gaussian blur of 5 fields
// (p, t, p*p, t*t, p*t) + ssim map + global mean, all in one kernel.
// Images: 32 x 1 x 512 x 512 fp32. Output: scalar fp32 = 1 - mean(ssim_map).

#define TW 64            // output tile width
#define TH 16            // output tile height
#define HALO 5
#define RW (TW + 2*HALO) // 74 raw cols
#define RH (TH + 2*HALO) // 26 raw rows
#define HSTRIDE (TW + 1) // 65: +1 pad -> conflict-free hblur writes/reads

__global__ __launch_bounds__(256, 3)
void ssim_main(const float* __restrict__ pred, const float* __restrict__ targ,
               float* __restrict__ acc) {
    // Gaussian window, sigma=1.5, ws=11, normalized (precomputed, ~1e-7 accurate)
    const float W[11] = {
        0.00102840f, 0.00759876f, 0.03600077f, 0.10936070f, 0.21300554f,
        0.26601173f,
        0.21300554f, 0.10936070f, 0.03600077f, 0.00759876f, 0.00102840f};

    __shared__ float sp[RH * RW];
    __shared__ float st[RH * RW];
    __shared__ float h[5][RH][HSTRIDE];
    __shared__ float wsum[4];

    const int tid = threadIdx.x;
    const int n = blockIdx.z;
    const float* __restrict__ pim = pred + (size_t)n * (512 * 512);
    const float* __restrict__ tim = targ + (size_t)n * (512 * 512);
    const int tr0 = blockIdx.y * TH - HALO;
    const int tc0 = blockIdx.x * TW - HALO;

    // ---- Phase 1: stage raw tile (zero-padded) ----
    for (int i = tid; i < RH * RW; i += 256) {
        int r = i / RW;
        int c = i - r * RW;
        int gr = tr0 + r, gc = tc0 + c;
        float p = 0.f, t = 0.f;
        if ((unsigned)gr < 512u && (unsigned)gc < 512u) {
            int g = (gr << 9) + gc;
            p = pim[g];
            t = tim[g];
        }
        sp[i] = p;
        st[i] = t;
    }
    __syncthreads();

    // ---- Phase 2: horizontal blur of 5 fields ----
    // 26 rows x 8 col-groups (8 outputs each) = 208 tasks
    if (tid < RH * (TW / 8)) {
        int r = tid >> 3;
        int cbase = (tid & 7) * 8;
        float p[18], t[18], pp[18], tt[18], pt[18];
#pragma unroll
        for (int k = 0; k < 18; ++k) {
            float a = sp[r * RW + cbase + k];
            float b = st[r * RW + cbase + k];
            p[k] = a; t[k] = b;
            pp[k] = a * a; tt[k] = b * b; pt[k] = a * b;
        }
#pragma unroll
        for (int i = 0; i < 8; ++i) {
            float s0 = 0.f, s1 = 0.f, s2 = 0.f, s3 = 0.f, s4 = 0.f;
#pragma unroll
            for (int k = 0; k < 11; ++k) {
                float w = W[k];
                s0 += w * p[i + k];
                s1 += w * t[i + k];
                s2 += w * pp[i + k];
                s3 += w * tt[i + k];
                s4 += w * pt[i + k];
            }
            h[0][r][cbase + i] = s0;
            h[1][r][cbase + i] = s1;
            h[2][r][cbase + i] = s2;
            h[3][r][cbase + i] = s3;
            h[4][r][cbase + i] = s4;
        }
    }
    __syncthreads();

    // ---- Phase 3: vertical blur + ssim ----
    // 64 cols x 4 row-groups (4 output rows each) = 256 tasks
    const int c = tid & 63;
    const int r0 = (tid >> 6) * 4;
    float mu[5][4];
#pragma unroll
    for (int f = 0; f < 5; ++f) {
        float win[14];
#pragma unroll
        for (int k = 0; k < 14; ++k) win[k] = h[f][r0 + k][c];
#pragma unroll
        for (int i = 0; i < 4; ++i) {
            float s = 0.f;
#pragma unroll
            for (int k = 0; k < 11; ++k) s += W[k] * win[i + k];
            mu[f][i] = s;
        }
    }

    float lsum = 0.f;
#pragma unroll
    for (int i = 0; i < 4; ++i) {
        float m1 = mu[0][i], m2 = mu[1][i];
        float m1s = m1 * m1, m2s = m2 * m2, m12 = m1 * m2;
        float s1 = mu[2][i] - m1s;
        float s2 = mu[3][i] - m2s;
        float s12 = mu[4][i] - m12;
        float num = (2.f * m12 + 1e-4f) * (2.f * s12 + 9e-4f);
        float den = (m1s + m2s + 1e-4f) * (s1 + s2 + 9e-4f);
        float rc = __builtin_amdgcn_rcpf(den);
        rc = rc * (2.f - den * rc);  // one Newton step
        lsum += num * rc;
    }

    // ---- Phase 4: reduce to one atomicAdd per block ----
#pragma unroll
    for (int off = 32; off > 0; off >>= 1)
        lsum += __shfl_down(lsum, off, 64);
    if ((tid & 63) == 0) wsum[tid >> 6] = lsum;
    __syncthreads();
    if (tid == 0) atomicAdd(acc, wsum[0] + wsum[1] + wsum[2] + wsum[3]);
}

__global__ void ssim_final(const float* __restrict__ acc,
                           float* __restrict__ out) {
    out[0] = 1.0f - acc[0] * (1.0f / 8388608.0f);  // N = 32*512*512
}

extern "C" void kernel_launch(void* const* d_in, const int* in_sizes, int n_in,
                              void* d_out, int out_size, void* d_ws,
                              size_t ws_size, hipStream_t stream) {
    const float* pred = (const float*)d_in[0];
    const float* targ = (const float*)d_in[1];
    float* out = (float*)d_out;
    float* acc = (float*)d_ws;

    hipMemsetAsync(acc, 0, sizeof(float), stream);
    dim3 grid(512 / TW, 512 / TH, 32);  // 8 x 32 x 32 = 8192 blocks
    ssim_main<<<grid, dim3(256), 0, stream>>>(pred, targ, acc);
    ssim_final<<<1, 1, 0, stream>>>(acc, out);
    (void)in_sizes; (void)n_in; (void)out_size; (void)d_ws; (void)ws_size;
}